// Round 1
// baseline (3361.615 us; speedup 1.0000x reference)
//
#include <hip/hip_runtime.h>
#include <cfloat>
#include <cstdint>
#include <cstddef>

#define NROWS 8192
#define HID 256
#define NCLS 5
#define TOPK 10

// ---------------------------------------------------------------------------
// Generic tiled fp32 GEMM: C[M,N] = act(A[M,K] @ op(B) + bias)
//   TB=false: B is [K,N] row-major (C = A@B)
//   TB=true : B is [N,K] row-major (C = A@B^T)
//   ACT: 0 = none, 1 = relu
// 64x64 tile, BK=16, 256 threads, 4x4 micro-tile per thread.
// ---------------------------------------------------------------------------
template<bool TB, bool BIAS, int ACT>
__global__ __launch_bounds__(256) void gemm_kernel(const float* __restrict__ A,
    const float* __restrict__ B, const float* __restrict__ bias,
    float* __restrict__ C, int M, int N, int K) {
  __shared__ float As[16][65];
  __shared__ float Bs[16][65];
  const int tid = threadIdx.x;
  const int tx = tid & 15, ty = tid >> 4;
  const int bm = blockIdx.y * 64, bn = blockIdx.x * 64;
  float acc[4][4] = {};
  for (int k0 = 0; k0 < K; k0 += 16) {
    // ---- load A tile: As[k][m]
    {
      const int m = tid >> 2;
      const int kq = (tid & 3) * 4;
      const int gm = bm + m, gk = k0 + kq;
      float a0 = 0.f, a1 = 0.f, a2 = 0.f, a3 = 0.f;
      if (gm < M) {
        const float* p = A + (size_t)gm * K + gk;
        if (gk + 3 < K) {
          float4 v4 = *(const float4*)p;
          a0 = v4.x; a1 = v4.y; a2 = v4.z; a3 = v4.w;
        } else {
          if (gk + 0 < K) a0 = p[0];
          if (gk + 1 < K) a1 = p[1];
          if (gk + 2 < K) a2 = p[2];
        }
      }
      As[kq + 0][m] = a0; As[kq + 1][m] = a1; As[kq + 2][m] = a2; As[kq + 3][m] = a3;
    }
    // ---- load B tile: Bs[k][n]
    if (!TB) {
      const int k = tid >> 4;
      const int nq = (tid & 15) * 4;
      const int gk = k0 + k, gn = bn + nq;
      float b0 = 0.f, b1 = 0.f, b2 = 0.f, b3 = 0.f;
      if (gk < K) {
        const float* p = B + (size_t)gk * N + gn;
        if (gn + 3 < N) {
          float4 v4 = *(const float4*)p;
          b0 = v4.x; b1 = v4.y; b2 = v4.z; b3 = v4.w;
        } else {
          if (gn + 0 < N) b0 = p[0];
          if (gn + 1 < N) b1 = p[1];
          if (gn + 2 < N) b2 = p[2];
        }
      }
      Bs[k][nq + 0] = b0; Bs[k][nq + 1] = b1; Bs[k][nq + 2] = b2; Bs[k][nq + 3] = b3;
    } else {
      const int n = tid >> 2;
      const int kq = (tid & 3) * 4;
      const int gn = bn + n, gk = k0 + kq;
      float b0 = 0.f, b1 = 0.f, b2 = 0.f, b3 = 0.f;
      if (gn < N) {
        const float* p = B + (size_t)gn * K + gk;
        if (gk + 3 < K) {
          float4 v4 = *(const float4*)p;
          b0 = v4.x; b1 = v4.y; b2 = v4.z; b3 = v4.w;
        } else {
          if (gk + 0 < K) b0 = p[0];
          if (gk + 1 < K) b1 = p[1];
          if (gk + 2 < K) b2 = p[2];
        }
      }
      Bs[kq + 0][n] = b0; Bs[kq + 1][n] = b1; Bs[kq + 2][n] = b2; Bs[kq + 3][n] = b3;
    }
    __syncthreads();
    #pragma unroll
    for (int kk = 0; kk < 16; ++kk) {
      float a0 = As[kk][ty * 4 + 0], a1 = As[kk][ty * 4 + 1];
      float a2 = As[kk][ty * 4 + 2], a3 = As[kk][ty * 4 + 3];
      float b0 = Bs[kk][tx * 4 + 0], b1 = Bs[kk][tx * 4 + 1];
      float b2 = Bs[kk][tx * 4 + 2], b3 = Bs[kk][tx * 4 + 3];
      acc[0][0] += a0 * b0; acc[0][1] += a0 * b1; acc[0][2] += a0 * b2; acc[0][3] += a0 * b3;
      acc[1][0] += a1 * b0; acc[1][1] += a1 * b1; acc[1][2] += a1 * b2; acc[1][3] += a1 * b3;
      acc[2][0] += a2 * b0; acc[2][1] += a2 * b1; acc[2][2] += a2 * b2; acc[2][3] += a2 * b3;
      acc[3][0] += a3 * b0; acc[3][1] += a3 * b1; acc[3][2] += a3 * b2; acc[3][3] += a3 * b3;
    }
    __syncthreads();
  }
  #pragma unroll
  for (int i = 0; i < 4; ++i) {
    const int gm = bm + ty * 4 + i;
    if (gm >= M) continue;
    #pragma unroll
    for (int jj = 0; jj < 4; ++jj) {
      const int gn = bn + tx * 4 + jj;
      if (gn >= N) continue;
      float v = acc[i][jj];
      if (BIAS) v += bias[gn];
      if (ACT == 1) v = fmaxf(v, 0.f);
      C[(size_t)gm * N + gn] = v;
    }
  }
}

// ---------------------------------------------------------------------------
// Training-mode BatchNorm1d over rows (biased var, eps=1e-5), in place.
// One block per column, 256 threads.
// ---------------------------------------------------------------------------
__global__ __launch_bounds__(256) void bn_kernel(float* __restrict__ F,
    const float* __restrict__ g, const float* __restrict__ b) {
  const int j = blockIdx.x, t = threadIdx.x;
  float s = 0.f, s2 = 0.f;
  for (int r = t; r < NROWS; r += 256) {
    float v = F[(size_t)r * HID + j];
    s += v; s2 += v * v;
  }
  __shared__ float sh1[256];
  __shared__ float sh2[256];
  sh1[t] = s; sh2[t] = s2;
  __syncthreads();
  for (int st = 128; st > 0; st >>= 1) {
    if (t < st) { sh1[t] += sh1[t + st]; sh2[t] += sh2[t + st]; }
    __syncthreads();
  }
  const float mu = sh1[0] / (float)NROWS;
  const float var = sh2[0] / (float)NROWS - mu * mu;
  const float rstd = rsqrtf(var + 1e-5f);
  const float gg = g[j], bb = b[j];
  for (int r = t; r < NROWS; r += 256) {
    const size_t o = (size_t)r * HID + j;
    F[o] = (F[o] - mu) * rstd * gg + bb;
  }
}

// ---------------------------------------------------------------------------
// L2 row-normalize: FN[r] = F[r] / max(||F[r]||, 1e-12). One block per row.
// ---------------------------------------------------------------------------
__global__ __launch_bounds__(256) void rownorm_kernel(const float* __restrict__ F,
    float* __restrict__ FN) {
  const int r = blockIdx.x, t = threadIdx.x;
  const float v = F[(size_t)r * HID + t];
  __shared__ float sh[256];
  sh[t] = v * v;
  __syncthreads();
  for (int st = 128; st > 0; st >>= 1) {
    if (t < st) sh[t] += sh[t + st];
    __syncthreads();
  }
  const float inv = 1.0f / fmaxf(sqrtf(sh[0]), 1e-12f);
  FN[(size_t)r * HID + t] = v * inv;
}

// ---------------------------------------------------------------------------
// Per-row top-10 (excluding self) over a sim stripe S[sr x NROWS].
// Writes L1-normalized neighbor values, indices, and diag (1/rowsum).
// One block (256 threads) per row.
// ---------------------------------------------------------------------------
__global__ __launch_bounds__(256) void topk_kernel(const float* __restrict__ S, int base,
    int* __restrict__ nidx, float* __restrict__ nval, float* __restrict__ dinv) {
  const int lr = blockIdx.x;
  const int row = base + lr;
  const float* srow = S + (size_t)lr * NROWS;
  const int t = threadIdx.x;
  float v[TOPK];
  int ix[TOPK];
  #pragma unroll
  for (int n = 0; n < TOPK; ++n) { v[n] = -FLT_MAX; ix[n] = -1; }
  for (int j = t; j < NROWS; j += 256) {
    if (j == row) continue;
    const float x = srow[j];
    if (x > v[TOPK - 1]) {
      #pragma unroll
      for (int p = TOPK - 1; p >= 1; --p) {
        if (x > v[p]) {
          const bool sh = x > v[p - 1];
          v[p] = sh ? v[p - 1] : x;
          ix[p] = sh ? ix[p - 1] : j;
        }
      }
      if (x > v[0]) { v[0] = x; ix[0] = j; }
    }
  }
  __shared__ float sval[256 * TOPK];
  __shared__ int sidx[256 * TOPK];
  __shared__ float rv[256];
  __shared__ int ri[256];
  __shared__ float gv[TOPK];
  __shared__ int gi[TOPK];
  #pragma unroll
  for (int n = 0; n < TOPK; ++n) { sval[t * TOPK + n] = v[n]; sidx[t * TOPK + n] = ix[n]; }
  int h = 0;
  __syncthreads();
  for (int sel = 0; sel < TOPK; ++sel) {
    rv[t] = (h < TOPK) ? sval[t * TOPK + h] : -FLT_MAX;
    ri[t] = t;
    __syncthreads();
    for (int s = 128; s > 0; s >>= 1) {
      if (t < s) {
        if (rv[t + s] > rv[t]) { rv[t] = rv[t + s]; ri[t] = ri[t + s]; }
      }
      __syncthreads();
    }
    const int w = ri[0];
    if (t == w) { gv[sel] = sval[t * TOPK + h]; gi[sel] = sidx[t * TOPK + h]; h++; }
    __syncthreads();
  }
  if (t == 0) {
    float sum = 1.0f;
    #pragma unroll
    for (int n = 0; n < TOPK; ++n) sum += fabsf(gv[n]);
    const float inv = 1.0f / fmaxf(sum, 1e-12f);
    dinv[row] = inv;
    #pragma unroll
    for (int n = 0; n < TOPK; ++n) {
      nval[row * TOPK + n] = gv[n] * inv;
      nidx[row * TOPK + n] = gi[n];
    }
  }
}

// ---------------------------------------------------------------------------
// Sparse adj (11 nnz/row) @ T + bias, leaky_relu(0.25). One block per row.
// ---------------------------------------------------------------------------
__global__ __launch_bounds__(256) void spmm_kernel(const float* __restrict__ T,
    const int* __restrict__ nidx, const float* __restrict__ nval,
    const float* __restrict__ dinv, const float* __restrict__ bias,
    float* __restrict__ H) {
  const int r = blockIdx.x, c = threadIdx.x;
  float acc = dinv[r] * T[(size_t)r * HID + c];
  #pragma unroll
  for (int n = 0; n < TOPK; ++n) {
    acc += nval[r * TOPK + n] * T[(size_t)nidx[r * TOPK + n] * HID + c];
  }
  acc += bias[c];
  H[(size_t)r * HID + c] = acc >= 0.f ? acc : 0.25f * acc;
}

// ---------------------------------------------------------------------------
// Classifier: L[r,c] = H[r] . W[:,c] + b[c]   (W is [HID, NCLS])
// ---------------------------------------------------------------------------
__global__ __launch_bounds__(256) void clf_kernel(const float* __restrict__ H,
    const float* __restrict__ W, const float* __restrict__ b,
    float* __restrict__ L) {
  const int id = blockIdx.x * 256 + threadIdx.x;
  if (id >= NROWS * NCLS) return;
  const int r = id / NCLS, c = id % NCLS;
  float s = b[c];
  const float* hr = H + (size_t)r * HID;
  for (int k = 0; k < HID; ++k) s += hr[k] * W[k * NCLS + c];
  L[id] = s;
}

// ---------------------------------------------------------------------------
// fused = sum_i softmax(attn)[i] * sigmoid(logits_i)
// ---------------------------------------------------------------------------
__global__ __launch_bounds__(256) void fuse_kernel(const float* __restrict__ L,
    const float* __restrict__ attn, float* __restrict__ fused) {
  const int id = blockIdx.x * 256 + threadIdx.x;
  if (id >= NROWS * NCLS) return;
  const float a0 = attn[0], a1 = attn[1], a2 = attn[2];
  const float m = fmaxf(a0, fmaxf(a1, a2));
  const float e0 = expf(a0 - m), e1 = expf(a1 - m), e2 = expf(a2 - m);
  const float inv = 1.0f / (e0 + e1 + e2);
  const float l0 = L[id];
  const float l1 = L[NROWS * NCLS + id];
  const float l2 = L[2 * NROWS * NCLS + id];
  const float s0 = 1.0f / (1.0f + expf(-l0));
  const float s1 = 1.0f / (1.0f + expf(-l1));
  const float s2 = 1.0f / (1.0f + expf(-l2));
  fused[id] = (e0 * s0 + e1 * s1 + e2 * s2) * inv;
}

// ---------------------------------------------------------------------------
// VCDN head: out = leaky(fused @ W1 + b1) @ W2 + b2. One block (128 thr)/row.
// W1 is [NCLS,128], W2 is [128,NCLS].
// ---------------------------------------------------------------------------
__global__ __launch_bounds__(128) void head_kernel(const float* __restrict__ fused,
    const float* __restrict__ W1, const float* __restrict__ b1,
    const float* __restrict__ W2, const float* __restrict__ b2,
    float* __restrict__ out) {
  const int r = blockIdx.x, t = threadIdx.x;
  __shared__ float f[NCLS];
  __shared__ float hh[128];
  if (t < NCLS) f[t] = fused[r * NCLS + t];
  __syncthreads();
  float s = b1[t];
  #pragma unroll
  for (int k = 0; k < NCLS; ++k) s += f[k] * W1[k * 128 + t];
  hh[t] = s >= 0.f ? s : 0.25f * s;
  __syncthreads();
  if (t < NCLS) {
    float o = b2[t];
    for (int k = 0; k < 128; ++k) o += hh[k] * W2[k * NCLS + t];
    out[r * NCLS + t] = o;
  }
}

// ---------------------------------------------------------------------------
extern "C" void kernel_launch(void* const* d_in, const int* in_sizes, int n_in,
                              void* d_out, int out_size, void* d_ws, size_t ws_size,
                              hipStream_t stream) {
  const float* x[3]    = {(const float*)d_in[0], (const float*)d_in[1], (const float*)d_in[2]};
  const float* encW[3] = {(const float*)d_in[3], (const float*)d_in[4], (const float*)d_in[5]};
  const float* enc_b = (const float*)d_in[6];
  const float* bn_g  = (const float*)d_in[7];
  const float* bn_b  = (const float*)d_in[8];
  const float* gc1W  = (const float*)d_in[9];
  const float* gc1b  = (const float*)d_in[10];
  const float* gc2W  = (const float*)d_in[11];
  const float* gc2b  = (const float*)d_in[12];
  const float* clfW  = (const float*)d_in[13];
  const float* clfb  = (const float*)d_in[14];
  const float* attn  = (const float*)d_in[15];
  const float* f1W   = (const float*)d_in[16];
  const float* f1b   = (const float*)d_in[17];
  const float* f2W   = (const float*)d_in[18];
  const float* f2b   = (const float*)d_in[19];
  float* out = (float*)d_out;

  // Workspace layout (floats)
  float* ws = (float*)d_ws;
  float* A = ws;                           // 8192*256 feat / h1
  float* B = A + (size_t)NROWS * HID;      // 8192*256 fn / h2
  float* C = B + (size_t)NROWS * HID;      // 8192*256 gemm temp
  int*   nidx = (int*)(C + (size_t)NROWS * HID);       // 8192*10
  float* nval = (float*)(nidx + (size_t)NROWS * TOPK); // 8192*10
  float* dinv = nval + (size_t)NROWS * TOPK;           // 8192
  float* logits = dinv + NROWS;                        // 3*8192*5
  float* fused = logits + (size_t)3 * NROWS * NCLS;    // 8192*5
  float* stripe = fused + (size_t)NROWS * NCLS;        // SR * 8192
  const size_t fixed_bytes = (size_t)(stripe - ws) * sizeof(float);
  const size_t avail = (ws_size > fixed_bytes) ? (ws_size - fixed_bytes) : 0;
  int SR = 64;
  while (SR < NROWS && (size_t)SR * 2 * NROWS * sizeof(float) <= avail) SR <<= 1;

  const dim3 blk(256);
  for (int i = 0; i < 3; ++i) {
    const int D = in_sizes[i] / NROWS;
    // encoder: A = relu(x @ W + b)
    {
      dim3 g((HID + 63) / 64, (NROWS + 63) / 64);
      gemm_kernel<false, true, 1><<<g, blk, 0, stream>>>(x[i], encW[i], enc_b + i * HID,
                                                         A, NROWS, HID, D);
    }
    // batchnorm in place
    bn_kernel<<<HID, blk, 0, stream>>>(A, bn_g + i * HID, bn_b + i * HID);
    // row-normalized features B = fn
    rownorm_kernel<<<NROWS, blk, 0, stream>>>(A, B);
    // sim stripes + topk -> sparse adjacency
    for (int s0 = 0; s0 < NROWS; s0 += SR) {
      dim3 g(NROWS / 64, SR / 64);
      gemm_kernel<true, false, 0><<<g, blk, 0, stream>>>(B + (size_t)s0 * HID, B, nullptr,
                                                         stripe, SR, NROWS, HID);
      topk_kernel<<<SR, blk, 0, stream>>>(stripe, s0, nidx, nval, dinv);
    }
    // gc1: C = feat @ W1 ; A = leaky(adj @ C + b1)
    {
      dim3 g(HID / 64, NROWS / 64);
      gemm_kernel<false, false, 0><<<g, blk, 0, stream>>>(A, gc1W + (size_t)i * HID * HID,
                                                          nullptr, C, NROWS, HID, HID);
    }
    spmm_kernel<<<NROWS, blk, 0, stream>>>(C, nidx, nval, dinv, gc1b + i * HID, A);
    // gc2: C = h1 @ W2 ; B = leaky(adj @ C + b2)
    {
      dim3 g(HID / 64, NROWS / 64);
      gemm_kernel<false, false, 0><<<g, blk, 0, stream>>>(A, gc2W + (size_t)i * HID * HID,
                                                          nullptr, C, NROWS, HID, HID);
    }
    spmm_kernel<<<NROWS, blk, 0, stream>>>(C, nidx, nval, dinv, gc2b + i * HID, B);
    // classifier
    clf_kernel<<<(NROWS * NCLS + 255) / 256, blk, 0, stream>>>(B, clfW + (size_t)i * HID * NCLS,
                                                               clfb + i * NCLS,
                                                               logits + (size_t)i * NROWS * NCLS);
  }
  fuse_kernel<<<(NROWS * NCLS + 255) / 256, blk, 0, stream>>>(logits, attn, fused);
  head_kernel<<<NROWS, dim3(128), 0, stream>>>(fused, f1W, f1b, f2W, f2b, out);
}

// Round 2
// 1821.244 us; speedup vs baseline: 1.8458x; 1.8458x over previous
//
#include <hip/hip_runtime.h>
#include <cfloat>
#include <cstdint>
#include <cstddef>

#define NROWS 8192
#define HID 256
#define NCLS 5
#define TOPK 10
#define CAND 16
#define KP 512      // packed K = 2*HID (hi|lo limbs)
#define TM 128
#define TN 128
#define BK 32

typedef __bf16 bf16x8 __attribute__((ext_vector_type(8)));
typedef float f32x4 __attribute__((ext_vector_type(4)));

__device__ inline ushort f2bf(float x) {
  unsigned u = __float_as_uint(x);
  unsigned r = (u + 0x7fffu + ((u >> 16) & 1u)) >> 16;  // RNE
  return (ushort)r;
}
__device__ inline float bf2f(ushort b) { return __uint_as_float(((unsigned)b) << 16); }

// ---------------------------------------------------------------------------
// Generic tiled fp32 GEMM (encoder + GCN weight GEMMs): C = act(A@B + bias)
// ---------------------------------------------------------------------------
template<bool BIAS, int ACT>
__global__ __launch_bounds__(256) void gemm_kernel(const float* __restrict__ A,
    const float* __restrict__ B, const float* __restrict__ bias,
    float* __restrict__ C, int M, int N, int K) {
  __shared__ float As[16][68];
  __shared__ float Bs[16][68];
  const int tid = threadIdx.x;
  const int tx = tid & 15, ty = tid >> 4;
  const int bm = blockIdx.y * 64, bn = blockIdx.x * 64;
  float acc[4][4] = {};
  for (int k0 = 0; k0 < K; k0 += 16) {
    {
      const int m = tid >> 2;
      const int kq = (tid & 3) * 4;
      const int gm = bm + m, gk = k0 + kq;
      float a0 = 0.f, a1 = 0.f, a2 = 0.f, a3 = 0.f;
      if (gm < M) {
        const float* p = A + (size_t)gm * K + gk;
        if (gk + 3 < K) {
          float4 v4 = *(const float4*)p;
          a0 = v4.x; a1 = v4.y; a2 = v4.z; a3 = v4.w;
        } else {
          if (gk + 0 < K) a0 = p[0];
          if (gk + 1 < K) a1 = p[1];
          if (gk + 2 < K) a2 = p[2];
        }
      }
      As[kq + 0][m] = a0; As[kq + 1][m] = a1; As[kq + 2][m] = a2; As[kq + 3][m] = a3;
    }
    {
      const int k = tid >> 4;
      const int nq = (tid & 15) * 4;
      const int gk = k0 + k, gn = bn + nq;
      float b0 = 0.f, b1 = 0.f, b2 = 0.f, b3 = 0.f;
      if (gk < K) {
        const float* p = B + (size_t)gk * N + gn;
        if (gn + 3 < N) {
          float4 v4 = *(const float4*)p;
          b0 = v4.x; b1 = v4.y; b2 = v4.z; b3 = v4.w;
        } else {
          if (gn + 0 < N) b0 = p[0];
          if (gn + 1 < N) b1 = p[1];
          if (gn + 2 < N) b2 = p[2];
        }
      }
      Bs[k][nq + 0] = b0; Bs[k][nq + 1] = b1; Bs[k][nq + 2] = b2; Bs[k][nq + 3] = b3;
    }
    __syncthreads();
    #pragma unroll
    for (int kk = 0; kk < 16; ++kk) {
      float a0 = As[kk][ty * 4 + 0], a1 = As[kk][ty * 4 + 1];
      float a2 = As[kk][ty * 4 + 2], a3 = As[kk][ty * 4 + 3];
      float b0 = Bs[kk][tx * 4 + 0], b1 = Bs[kk][tx * 4 + 1];
      float b2 = Bs[kk][tx * 4 + 2], b3 = Bs[kk][tx * 4 + 3];
      acc[0][0] += a0 * b0; acc[0][1] += a0 * b1; acc[0][2] += a0 * b2; acc[0][3] += a0 * b3;
      acc[1][0] += a1 * b0; acc[1][1] += a1 * b1; acc[1][2] += a1 * b2; acc[1][3] += a1 * b3;
      acc[2][0] += a2 * b0; acc[2][1] += a2 * b1; acc[2][2] += a2 * b2; acc[2][3] += a2 * b3;
      acc[3][0] += a3 * b0; acc[3][1] += a3 * b1; acc[3][2] += a3 * b2; acc[3][3] += a3 * b3;
    }
    __syncthreads();
  }
  #pragma unroll
  for (int i = 0; i < 4; ++i) {
    const int gm = bm + ty * 4 + i;
    if (gm >= M) continue;
    #pragma unroll
    for (int jj = 0; jj < 4; ++jj) {
      const int gn = bn + tx * 4 + jj;
      if (gn >= N) continue;
      float v = acc[i][jj];
      if (BIAS) v += bias[gn];
      if (ACT == 1) v = fmaxf(v, 0.f);
      C[(size_t)gm * N + gn] = v;
    }
  }
}

// ---------------------------------------------------------------------------
// BatchNorm1d (training stats, biased var, eps=1e-5), in place.
// ---------------------------------------------------------------------------
__global__ __launch_bounds__(256) void bn_kernel(float* __restrict__ F,
    const float* __restrict__ g, const float* __restrict__ b) {
  const int j = blockIdx.x, t = threadIdx.x;
  float s = 0.f, s2 = 0.f;
  for (int r = t; r < NROWS; r += 256) {
    float v = F[(size_t)r * HID + j];
    s += v; s2 += v * v;
  }
  __shared__ float sh1[256];
  __shared__ float sh2[256];
  sh1[t] = s; sh2[t] = s2;
  __syncthreads();
  for (int st = 128; st > 0; st >>= 1) {
    if (t < st) { sh1[t] += sh1[t + st]; sh2[t] += sh2[t + st]; }
    __syncthreads();
  }
  const float mu = sh1[0] / (float)NROWS;
  const float var = sh2[0] / (float)NROWS - mu * mu;
  const float rstd = rsqrtf(var + 1e-5f);
  const float gg = g[j], bb = b[j];
  for (int r = t; r < NROWS; r += 256) {
    const size_t o = (size_t)r * HID + j;
    F[o] = (F[o] - mu) * rstd * gg + bb;
  }
}

// ---------------------------------------------------------------------------
// L2 row-normalize fn = feat/||feat||.
// ---------------------------------------------------------------------------
__global__ __launch_bounds__(256) void rownorm_kernel(const float* __restrict__ F,
    float* __restrict__ FN) {
  const int r = blockIdx.x, t = threadIdx.x;
  const float v = F[(size_t)r * HID + t];
  __shared__ float sh[256];
  sh[t] = v * v;
  __syncthreads();
  for (int st = 128; st > 0; st >>= 1) {
    if (t < st) sh[t] += sh[t + st];
    __syncthreads();
  }
  const float inv = 1.0f / fmaxf(sqrtf(sh[0]), 1e-12f);
  FN[(size_t)r * HID + t] = v * inv;
}

// ---------------------------------------------------------------------------
// Pack fn into two-limb bf16: P[r] = [bf16(x) | bf16(x - hi)], K = 512.
// ---------------------------------------------------------------------------
__global__ __launch_bounds__(256) void pack_kernel(const float* __restrict__ FN,
    ushort* __restrict__ P) {
  const int id = blockIdx.x * 256 + threadIdx.x;
  const int r = id >> 8, k = id & 255;
  const float x = FN[id];
  const ushort h = f2bf(x);
  const ushort l = f2bf(x - bf2f(h));
  P[(size_t)r * KP + k] = h;
  P[(size_t)r * KP + HID + k] = l;
}

// ---------------------------------------------------------------------------
// sim stripe = P[mbase+..] @ P^T via bf16 MFMA 16x16x32, K=512.
// 128x128 tile, 4 waves (each 64x64 = 4x4 frags), BK=32, XOR-swizzled LDS.
// ---------------------------------------------------------------------------
__global__ __launch_bounds__(256) void simgemm_kernel(const ushort* __restrict__ P,
    float* __restrict__ C, int mbase) {
  __shared__ ushort As[TM * BK];  // 512 slots of 8 bf16 (16B), swizzled
  __shared__ ushort Bs[TN * BK];
  const int tid = threadIdx.x;
  const int wave = tid >> 6, lane = tid & 63;
  const int bmr = blockIdx.y * TM;          // local stripe row base
  const int bm = mbase + bmr;               // global row base (A side)
  const int bn = blockIdx.x * TN;           // global row base (B side)
  const int wr = (wave >> 1) * 64;
  const int wc = (wave & 1) * 64;

  f32x4 acc[4][4];
  const f32x4 zero = {0.f, 0.f, 0.f, 0.f};
  #pragma unroll
  for (int i = 0; i < 4; ++i)
    #pragma unroll
    for (int j = 0; j < 4; ++j) acc[i][j] = zero;

  // staging slots for this thread (physical slot index -> (row, k-group))
  const int p0 = tid, p1 = tid + 256;
  const int r0 = p0 >> 2, kl0 = (p0 & 3) ^ ((r0 & 3) ^ ((r0 >> 2) & 1));
  const int r1 = p1 >> 2, kl1 = (p1 & 3) ^ ((r1 & 3) ^ ((r1 >> 2) & 1));
  const ushort* pa0 = P + (size_t)(bm + r0) * KP + kl0 * 8;
  const ushort* pa1 = P + (size_t)(bm + r1) * KP + kl1 * 8;
  const ushort* pb0 = P + (size_t)(bn + r0) * KP + kl0 * 8;
  const ushort* pb1 = P + (size_t)(bn + r1) * KP + kl1 * 8;

  for (int k0 = 0; k0 < KP; k0 += BK) {
    const uint4 va0 = *(const uint4*)(pa0 + k0);
    const uint4 va1 = *(const uint4*)(pa1 + k0);
    const uint4 vb0 = *(const uint4*)(pb0 + k0);
    const uint4 vb1 = *(const uint4*)(pb1 + k0);
    __syncthreads();
    *(uint4*)&As[p0 * 8] = va0;
    *(uint4*)&As[p1 * 8] = va1;
    *(uint4*)&Bs[p0 * 8] = vb0;
    *(uint4*)&Bs[p1 * 8] = vb1;
    __syncthreads();
    bf16x8 af[4], bf[4];
    const int kg = lane >> 4;
    #pragma unroll
    for (int f = 0; f < 4; ++f) {
      const int m = wr + f * 16 + (lane & 15);
      const int sa = m * 4 + (kg ^ (m & 3) ^ ((m >> 2) & 1));
      af[f] = *(const bf16x8*)&As[sa * 8];
      const int n = wc + f * 16 + (lane & 15);
      const int sb = n * 4 + (kg ^ (n & 3) ^ ((n >> 2) & 1));
      bf[f] = *(const bf16x8*)&Bs[sb * 8];
    }
    #pragma unroll
    for (int fr = 0; fr < 4; ++fr)
      #pragma unroll
      for (int fc = 0; fc < 4; ++fc)
        acc[fr][fc] = __builtin_amdgcn_mfma_f32_16x16x32_bf16(af[fr], bf[fc], acc[fr][fc], 0, 0, 0);
  }
  // epilogue: C layout col=lane&15, row=(lane>>4)*4+reg
  const int cq = lane >> 4, cc = lane & 15;
  #pragma unroll
  for (int fr = 0; fr < 4; ++fr) {
    #pragma unroll
    for (int fc = 0; fc < 4; ++fc) {
      const int rb = bmr + wr + fr * 16 + cq * 4;
      const int col = bn + wc + fc * 16 + cc;
      float* cp = C + (size_t)rb * NROWS + col;
      cp[0] = acc[fr][fc].x;
      cp[(size_t)1 * NROWS] = acc[fr][fc].y;
      cp[(size_t)2 * NROWS] = acc[fr][fc].z;
      cp[(size_t)3 * NROWS] = acc[fr][fc].w;
    }
  }
}

// ---------------------------------------------------------------------------
// Per-row top-K from approx sim stripe, one WAVE per row.
// 1) per-lane sorted top-16 over its 128 columns (self masked)
// 2) wave argmax+pop-front merge -> 16 candidates (shuffles only)
// 3) exact fp32 dot recompute for the 16 candidates (4 lanes each)
// 4) exact top-10 selection, L1-normalize, store neighbor lists + diag
// ---------------------------------------------------------------------------
__global__ __launch_bounds__(256) void topk_kernel(const float* __restrict__ S, int base,
    const float* __restrict__ FN, int* __restrict__ nidx, float* __restrict__ nval,
    float* __restrict__ dinv) {
  const int wave = threadIdx.x >> 6, lane = threadIdx.x & 63;
  const int lr = blockIdx.x * 4 + wave;
  const int row = base + lr;
  const float* srow = S + (size_t)lr * NROWS;

  float v[CAND];
  int ix[CAND];
  #pragma unroll
  for (int n = 0; n < CAND; ++n) { v[n] = -FLT_MAX; ix[n] = -1; }
  for (int j = lane; j < NROWS; j += 64) {
    const float x = (j == row) ? -FLT_MAX : srow[j];
    if (x > v[CAND - 1]) {
      #pragma unroll
      for (int p = CAND - 1; p >= 1; --p) {
        if (x > v[p]) {
          const bool sh = x > v[p - 1];
          v[p] = sh ? v[p - 1] : x;
          ix[p] = sh ? ix[p - 1] : j;
        }
      }
      if (x > v[0]) { v[0] = x; ix[0] = j; }
    }
  }
  // wave merge: 16 rounds of butterfly argmax over heads, winner pops front
  int my_cand = 0;  // the candidate index this lane will refine (lane>>2)
  #pragma unroll
  for (int sel = 0; sel < CAND; ++sel) {
    float bv = v[0];
    int bl = lane;
    #pragma unroll
    for (int s = 1; s < 64; s <<= 1) {
      const float ov = __shfl_xor(bv, s);
      const int ol = __shfl_xor(bl, s);
      if (ov > bv || (ov == bv && ol < bl)) { bv = ov; bl = ol; }
    }
    const int ci = __shfl(ix[0], bl);
    if ((lane >> 2) == sel) my_cand = ci;
    if (lane == bl) {
      #pragma unroll
      for (int p = 0; p < CAND - 1; ++p) { v[p] = v[p + 1]; ix[p] = ix[p + 1]; }
      v[CAND - 1] = -FLT_MAX;
      ix[CAND - 1] = -1;
    }
  }
  // exact fp32 refinement
  __shared__ float fnrow[4][HID];
  __shared__ float ev[4][CAND];
  __shared__ int eid[4][CAND];
  ((float4*)fnrow[wave])[lane] = ((const float4*)(FN + (size_t)row * HID))[lane];
  __syncthreads();
  const int c = lane >> 2, q = lane & 3;
  {
    float s = 0.f;
    const float* fc = FN + (size_t)my_cand * HID;
    const float* fr = fnrow[wave] + q * 64;
    const float* fcq = fc + q * 64;
    #pragma unroll 8
    for (int k = 0; k < 64; ++k) s += fr[k] * fcq[k];
    s += __shfl_xor(s, 1);
    s += __shfl_xor(s, 2);
    if (q == 0) { ev[wave][c] = s; eid[wave][c] = my_cand; }
  }
  __syncthreads();
  if (lane == 0) {
    unsigned used = 0;
    float outv[TOPK];
    int outi[TOPK];
    float sum = 1.0f;  // diag contributes 1
    #pragma unroll
    for (int sel = 0; sel < TOPK; ++sel) {
      float best = -FLT_MAX;
      int bi = 0;
      #pragma unroll
      for (int k = 0; k < CAND; ++k) {
        if (!((used >> k) & 1u) && ev[wave][k] > best) { best = ev[wave][k]; bi = k; }
      }
      used |= 1u << bi;
      outv[sel] = best;
      outi[sel] = eid[wave][bi];
      sum += fabsf(best);
    }
    const float inv = 1.0f / fmaxf(sum, 1e-12f);
    dinv[row] = inv;
    #pragma unroll
    for (int sel = 0; sel < TOPK; ++sel) {
      nval[row * TOPK + sel] = outv[sel] * inv;
      nidx[row * TOPK + sel] = outi[sel];
    }
  }
}

// ---------------------------------------------------------------------------
// Sparse adj (11 nnz/row) @ T + bias, leaky_relu(0.25).
// ---------------------------------------------------------------------------
__global__ __launch_bounds__(256) void spmm_kernel(const float* __restrict__ T,
    const int* __restrict__ nidx, const float* __restrict__ nval,
    const float* __restrict__ dinv, const float* __restrict__ bias,
    float* __restrict__ H) {
  const int r = blockIdx.x, c = threadIdx.x;
  float acc = dinv[r] * T[(size_t)r * HID + c];
  #pragma unroll
  for (int n = 0; n < TOPK; ++n) {
    acc += nval[r * TOPK + n] * T[(size_t)nidx[r * TOPK + n] * HID + c];
  }
  acc += bias[c];
  H[(size_t)r * HID + c] = acc >= 0.f ? acc : 0.25f * acc;
}

__global__ __launch_bounds__(256) void clf_kernel(const float* __restrict__ H,
    const float* __restrict__ W, const float* __restrict__ b,
    float* __restrict__ L) {
  const int id = blockIdx.x * 256 + threadIdx.x;
  if (id >= NROWS * NCLS) return;
  const int r = id / NCLS, c = id % NCLS;
  float s = b[c];
  const float* hr = H + (size_t)r * HID;
  for (int k = 0; k < HID; ++k) s += hr[k] * W[k * NCLS + c];
  L[id] = s;
}

__global__ __launch_bounds__(256) void fuse_kernel(const float* __restrict__ L,
    const float* __restrict__ attn, float* __restrict__ fused) {
  const int id = blockIdx.x * 256 + threadIdx.x;
  if (id >= NROWS * NCLS) return;
  const float a0 = attn[0], a1 = attn[1], a2 = attn[2];
  const float m = fmaxf(a0, fmaxf(a1, a2));
  const float e0 = expf(a0 - m), e1 = expf(a1 - m), e2 = expf(a2 - m);
  const float inv = 1.0f / (e0 + e1 + e2);
  const float l0 = L[id];
  const float l1 = L[NROWS * NCLS + id];
  const float l2 = L[2 * NROWS * NCLS + id];
  const float s0 = 1.0f / (1.0f + expf(-l0));
  const float s1 = 1.0f / (1.0f + expf(-l1));
  const float s2 = 1.0f / (1.0f + expf(-l2));
  fused[id] = (e0 * s0 + e1 * s1 + e2 * s2) * inv;
}

__global__ __launch_bounds__(128) void head_kernel(const float* __restrict__ fused,
    const float* __restrict__ W1, const float* __restrict__ b1,
    const float* __restrict__ W2, const float* __restrict__ b2,
    float* __restrict__ out) {
  const int r = blockIdx.x, t = threadIdx.x;
  __shared__ float f[NCLS];
  __shared__ float hh[128];
  if (t < NCLS) f[t] = fused[r * NCLS + t];
  __syncthreads();
  float s = b1[t];
  #pragma unroll
  for (int k = 0; k < NCLS; ++k) s += f[k] * W1[k * 128 + t];
  hh[t] = s >= 0.f ? s : 0.25f * s;
  __syncthreads();
  if (t < NCLS) {
    float o = b2[t];
    for (int k = 0; k < 128; ++k) o += hh[k] * W2[k * NCLS + t];
    out[r * NCLS + t] = o;
  }
}

// ---------------------------------------------------------------------------
extern "C" void kernel_launch(void* const* d_in, const int* in_sizes, int n_in,
                              void* d_out, int out_size, void* d_ws, size_t ws_size,
                              hipStream_t stream) {
  const float* x[3]    = {(const float*)d_in[0], (const float*)d_in[1], (const float*)d_in[2]};
  const float* encW[3] = {(const float*)d_in[3], (const float*)d_in[4], (const float*)d_in[5]};
  const float* enc_b = (const float*)d_in[6];
  const float* bn_g  = (const float*)d_in[7];
  const float* bn_b  = (const float*)d_in[8];
  const float* gc1W  = (const float*)d_in[9];
  const float* gc1b  = (const float*)d_in[10];
  const float* gc2W  = (const float*)d_in[11];
  const float* gc2b  = (const float*)d_in[12];
  const float* clfW  = (const float*)d_in[13];
  const float* clfb  = (const float*)d_in[14];
  const float* attn  = (const float*)d_in[15];
  const float* f1W   = (const float*)d_in[16];
  const float* f1b   = (const float*)d_in[17];
  const float* f2W   = (const float*)d_in[18];
  const float* f2b   = (const float*)d_in[19];
  float* out = (float*)d_out;

  // Workspace layout
  float* ws = (float*)d_ws;
  float* A = ws;                           // 8192*256 feat / h1
  float* B = A + (size_t)NROWS * HID;      // 8192*256 fn / h2
  float* C = B + (size_t)NROWS * HID;      // 8192*256 gemm temp
  int*   nidx = (int*)(C + (size_t)NROWS * HID);       // 8192*10
  float* nval = (float*)(nidx + (size_t)NROWS * TOPK); // 8192*10
  float* dinv = nval + (size_t)NROWS * TOPK;           // 8192
  float* logits = dinv + NROWS;                        // 3*8192*5
  float* fused = logits + (size_t)3 * NROWS * NCLS;    // 8192*5
  ushort* Pb = (ushort*)(fused + (size_t)NROWS * NCLS); // 8192*512 bf16 limbs
  float* stripe = (float*)(Pb + (size_t)NROWS * KP);    // SR * 8192
  const size_t fixed_bytes = (size_t)((char*)stripe - (char*)ws);
  const size_t avail = (ws_size > fixed_bytes) ? (ws_size - fixed_bytes) : 0;
  int SR = 128;
  while (SR < NROWS && (size_t)SR * 2 * NROWS * sizeof(float) <= avail) SR <<= 1;

  const dim3 blk(256);
  for (int i = 0; i < 3; ++i) {
    const int D = in_sizes[i] / NROWS;
    // encoder: A = relu(x @ W + b)
    {
      dim3 g((HID + 63) / 64, (NROWS + 63) / 64);
      gemm_kernel<true, 1><<<g, blk, 0, stream>>>(x[i], encW[i], enc_b + i * HID,
                                                  A, NROWS, HID, D);
    }
    bn_kernel<<<HID, blk, 0, stream>>>(A, bn_g + i * HID, bn_b + i * HID);
    rownorm_kernel<<<NROWS, blk, 0, stream>>>(A, B);
    // two-limb bf16 pack of fn
    pack_kernel<<<NROWS * HID / 256, blk, 0, stream>>>(B, Pb);
    // sim stripes (MFMA) + per-row top-k with exact refinement
    for (int s0 = 0; s0 < NROWS; s0 += SR) {
      dim3 g(NROWS / TN, SR / TM);
      simgemm_kernel<<<g, blk, 0, stream>>>(Pb, stripe, s0);
      topk_kernel<<<SR / 4, blk, 0, stream>>>(stripe, s0, B, nidx, nval, dinv);
    }
    // gc1
    {
      dim3 g(HID / 64, NROWS / 64);
      gemm_kernel<false, 0><<<g, blk, 0, stream>>>(A, gc1W + (size_t)i * HID * HID,
                                                   nullptr, C, NROWS, HID, HID);
    }
    spmm_kernel<<<NROWS, blk, 0, stream>>>(C, nidx, nval, dinv, gc1b + i * HID, A);
    // gc2
    {
      dim3 g(HID / 64, NROWS / 64);
      gemm_kernel<false, 0><<<g, blk, 0, stream>>>(A, gc2W + (size_t)i * HID * HID,
                                                   nullptr, C, NROWS, HID, HID);
    }
    spmm_kernel<<<NROWS, blk, 0, stream>>>(C, nidx, nval, dinv, gc2b + i * HID, B);
    clf_kernel<<<(NROWS * NCLS + 255) / 256, blk, 0, stream>>>(B, clfW + (size_t)i * HID * NCLS,
                                                               clfb + i * NCLS,
                                                               logits + (size_t)i * NROWS * NCLS);
  }
  fuse_kernel<<<(NROWS * NCLS + 255) / 256, blk, 0, stream>>>(logits, attn, fused);
  head_kernel<<<NROWS, dim3(128), 0, stream>>>(fused, f1W, f1b, f2W, f2b, out);
}